// Round 6
// baseline (580.425 us; speedup 1.0000x reference)
//
#include <hip/hip_runtime.h>

#define N_VAR   100000
#define N_CSTR  50000
#define NEDGE   1000000
#define DIM     64

// Two-level scan geometry: 1024 elements per block.
#define NB_N 98    // ceil(100000/1024)
#define NB_C 49    // ceil(50000/1024)
#define NB_T 147

// Counters are padded to one per 64B cache line (stride 16 ints) so atomics
// to different counters never hit the same line (same-line atomics serialize
// at the TCC bank).
#define CPAD 16

// ---------------------------------------------------------------------------
// Workspace layout (4-byte units), ~35.8 MB:
//   0:          deg_node_pad 1600000 (int, stride 16) -- zeroed
//   1600000:    deg_cstr_pad  800000 (int, stride 16) -- zeroed
//   2400000:    stats            256 (float)          -- zeroed
//   2400256:    ab               256 (float)
//   2400512:    off_node      100001 (int, compact)
//   2500516:    off_cstr       50001 (int, compact)
//   2550520:    cur_node_pad 1600000 (int, stride 16)
//   4150520:    cur_cstr_pad  800000 (int, stride 16)
//   4950520:    bsum             160 (int)
//   4950680:    bpref            160 (int)
//   4950840:    ent_node     1000000 (int2)
//   6950840:    ent_cstr     1000000 (int2)
// agg rows live in d_out; out_k rewrites d_out in place.
// ---------------------------------------------------------------------------
#define OFF_DEG_N   0
#define OFF_DEG_C   1600000
#define OFF_STATS   2400000
#define OFF_AB      2400256
#define OFF_OFF_N   2400512
#define OFF_OFF_C   2500516
#define OFF_CUR_N   2550520
#define OFF_CUR_C   4150520
#define OFF_BSUM    4950520
#define OFF_BPREF   4950680
#define OFF_ENT_N   4950840
#define OFF_ENT_C   6950840
#define WS_ZERO_N   2400512   // ints to zero (padded deg arrays + stats)

// ---------------------------------------------------------------------------
// BN column stats.
// ---------------------------------------------------------------------------
__global__ __launch_bounds__(256) void bn_stats_k(const float* __restrict__ x, int n,
                                                  float* __restrict__ stats) {
  int c = threadIdx.x & 63;
  int rg = threadIdx.x >> 6;
  float s = 0.f, q = 0.f;
  for (int r = blockIdx.x * 4 + rg; r < n; r += gridDim.x * 4) {
    float v = x[r * DIM + c];
    s += v;
    q += v * v;
  }
  __shared__ float sb[256], qb[256];
  sb[threadIdx.x] = s;
  qb[threadIdx.x] = q;
  __syncthreads();
  if (rg == 0) {
    s = sb[c] + sb[c + 64] + sb[c + 128] + sb[c + 192];
    q = qb[c] + qb[c + 64] + qb[c + 128] + qb[c + 192];
    atomicAdd(&stats[c], s);
    atomicAdd(&stats[64 + c], q);
  }
}

__global__ void bn_finalize_k(const float* __restrict__ stats,
                              const float* __restrict__ gn, const float* __restrict__ bn,
                              const float* __restrict__ gc, const float* __restrict__ bc,
                              float* __restrict__ ab) {
  int t = threadIdx.x;  // 0..127
  int c = t & 63;
  bool isC = t >= 64;
  const float* st = stats + (isC ? 128 : 0);
  float n = isC ? (float)N_CSTR : (float)N_VAR;
  float mean = st[c] / n;
  float var = st[64 + c] / n - mean * mean;
  float g = isC ? gc[c] : gn[c];
  float be = isC ? bc[c] : bn[c];
  float a = g * rsqrtf(var + 1e-5f);
  float b = be - mean * a;
  float* o = ab + (isC ? 128 : 0);
  o[c] = a;
  o[64 + c] = b;
}

// ---------------------------------------------------------------------------
// Degree histogram: 4 edges/thread, padded counters (1 per 64B line).
// ---------------------------------------------------------------------------
__global__ __launch_bounds__(256) void hist_k(const int4* __restrict__ es4,
                                              const int4* __restrict__ ed4,
                                              int* __restrict__ deg_node,
                                              int* __restrict__ deg_cstr) {
  int g = blockIdx.x * blockDim.x + threadIdx.x;
  if (g < NEDGE / 4) {
    int4 d = ed4[g];
    int4 s = es4[g];
    atomicAdd(&deg_node[d.x * CPAD], 1);
    atomicAdd(&deg_node[d.y * CPAD], 1);
    atomicAdd(&deg_node[d.z * CPAD], 1);
    atomicAdd(&deg_node[d.w * CPAD], 1);
    atomicAdd(&deg_cstr[s.x * CPAD], 1);
    atomicAdd(&deg_cstr[s.y * CPAD], 1);
    atomicAdd(&deg_cstr[s.z * CPAD], 1);
    atomicAdd(&deg_cstr[s.w * CPAD], 1);
  }
}

// ---------------------------------------------------------------------------
// Two-level scan, phase 1: per-block (1024-element) sums -> bsum[147].
// Reads the padded degree arrays (stride CPAD).
// ---------------------------------------------------------------------------
__global__ __launch_bounds__(256) void scan_part_k(int* __restrict__ ws) {
  int b = blockIdx.x;
  int seg = (b >= NB_N);
  const int* deg = ws + (seg ? OFF_DEG_C : OFF_DEG_N);
  int n = seg ? N_CSTR : N_VAR;
  int lb = seg ? b - NB_N : b;
  int base = lb * 1024 + threadIdx.x * 4;
  int s = 0;
#pragma unroll
  for (int j = 0; j < 4; ++j)
    if (base + j < n) s += deg[(base + j) * CPAD];
  __shared__ int sb[256];
  sb[threadIdx.x] = s;
  __syncthreads();
  for (int d = 128; d > 0; d >>= 1) {
    if (threadIdx.x < d) sb[threadIdx.x] += sb[threadIdx.x + d];
    __syncthreads();
  }
  if (threadIdx.x == 0) ws[OFF_BSUM + b] = sb[0];
}

// ---------------------------------------------------------------------------
// Phase 2: one block scans the 147 block sums; seeds off[n].
// ---------------------------------------------------------------------------
__global__ __launch_bounds__(256) void scan_meta_k(int* __restrict__ ws) {
  int t = threadIdx.x;
  int seg = t >> 7;
  int lt = t & 127;
  int nb = seg ? NB_C : NB_N;
  int v = (lt < nb) ? ws[OFF_BSUM + (seg ? NB_N : 0) + lt] : 0;
  __shared__ int sb[256];
  sb[t] = v;
  __syncthreads();
  for (int d = 1; d < 128; d <<= 1) {
    int u = (lt >= d) ? sb[t - d] : 0;
    __syncthreads();
    sb[t] += u;
    __syncthreads();
  }
  if (lt < nb) ws[OFF_BPREF + (seg ? NB_N : 0) + lt] = sb[t] - v;
  if (t == 0) {
    ws[OFF_OFF_N + N_VAR] = NEDGE;
    ws[OFF_OFF_C + N_CSTR] = NEDGE;
  }
}

// ---------------------------------------------------------------------------
// Phase 3: local exclusive scan + block prefix -> off[] (compact) and
// cur[] (padded, for fill's atomics).
// ---------------------------------------------------------------------------
__global__ __launch_bounds__(256) void scan_apply_k(int* __restrict__ ws) {
  int b = blockIdx.x;
  int seg = (b >= NB_N);
  const int* deg = ws + (seg ? OFF_DEG_C : OFF_DEG_N);
  int* off = ws + (seg ? OFF_OFF_C : OFF_OFF_N);
  int* cur = ws + (seg ? OFF_CUR_C : OFF_CUR_N);
  int n = seg ? N_CSTR : N_VAR;
  int lb = seg ? b - NB_N : b;
  int base = lb * 1024 + threadIdx.x * 4;
  int v0 = 0, v1 = 0, v2 = 0, v3 = 0;
  if (base < n) v0 = deg[base * CPAD];
  if (base + 1 < n) v1 = deg[(base + 1) * CPAD];
  if (base + 2 < n) v2 = deg[(base + 2) * CPAD];
  if (base + 3 < n) v3 = deg[(base + 3) * CPAD];
  int s = v0 + v1 + v2 + v3;
  __shared__ int sb[256];
  sb[threadIdx.x] = s;
  __syncthreads();
  for (int d = 1; d < 256; d <<= 1) {
    int u = (threadIdx.x >= d) ? sb[threadIdx.x - d] : 0;
    __syncthreads();
    sb[threadIdx.x] += u;
    __syncthreads();
  }
  int excl = sb[threadIdx.x] - s + ws[OFF_BPREF + b];
  int o0 = excl, o1 = o0 + v0, o2 = o1 + v1, o3 = o2 + v2;
  if (base < n)     { off[base] = o0;     cur[base * CPAD] = o0; }
  if (base + 1 < n) { off[base + 1] = o1; cur[(base + 1) * CPAD] = o1; }
  if (base + 2 < n) { off[base + 2] = o2; cur[(base + 2) * CPAD] = o2; }
  if (base + 3 < n) { off[base + 3] = o3; cur[(base + 3) * CPAD] = o3; }
}

// ---------------------------------------------------------------------------
// Fill CSR buckets: padded counters + NON-TEMPORAL entry stores (bypass L2 so
// the fabric/LLC merges partial lines instead of 8x cross-XCD line thrash).
// ---------------------------------------------------------------------------
__device__ __forceinline__ void nt_store_ent(int2* p, int idx, int wbits) {
  long v = (long)(unsigned)idx | ((long)(unsigned)wbits << 32);
  __builtin_nontemporal_store(v, (long*)p);
}

__global__ __launch_bounds__(256) void fill_k(const int4* __restrict__ es4,
                                              const int4* __restrict__ ed4,
                                              const float4* __restrict__ ea4,
                                              int* __restrict__ cur_node,
                                              int* __restrict__ cur_cstr,
                                              int2* __restrict__ ent_node,
                                              int2* __restrict__ ent_cstr) {
  int g = blockIdx.x * blockDim.x + threadIdx.x;
  if (g >= NEDGE / 4) return;
  int4 s = es4[g];
  int4 d = ed4[g];
  float4 w = ea4[g];
  int p0 = atomicAdd(&cur_node[d.x * CPAD], 1);
  int p1 = atomicAdd(&cur_node[d.y * CPAD], 1);
  int p2 = atomicAdd(&cur_node[d.z * CPAD], 1);
  int p3 = atomicAdd(&cur_node[d.w * CPAD], 1);
  int q0 = atomicAdd(&cur_cstr[s.x * CPAD], 1);
  int q1 = atomicAdd(&cur_cstr[s.y * CPAD], 1);
  int q2 = atomicAdd(&cur_cstr[s.z * CPAD], 1);
  int q3 = atomicAdd(&cur_cstr[s.w * CPAD], 1);
  nt_store_ent(&ent_node[p0], s.x, __float_as_int(w.x));
  nt_store_ent(&ent_node[p1], s.y, __float_as_int(w.y));
  nt_store_ent(&ent_node[p2], s.z, __float_as_int(w.z));
  nt_store_ent(&ent_node[p3], s.w, __float_as_int(w.w));
  nt_store_ent(&ent_cstr[q0], d.x, __float_as_int(w.x));
  nt_store_ent(&ent_cstr[q1], d.y, __float_as_int(w.y));
  nt_store_ent(&ent_cstr[q2], d.z, __float_as_int(w.z));
  nt_store_ent(&ent_cstr[q3], d.w, __float_as_int(w.w));
}

// ---------------------------------------------------------------------------
// Gather: one wave per destination row, lane = column, unroll-8, dual acc.
// ---------------------------------------------------------------------------
__global__ __launch_bounds__(256) void gather_k(
    const float* __restrict__ srcf, const int2* __restrict__ ent,
    const int* __restrict__ off, const float* __restrict__ ab_src,
    float* __restrict__ agg, int n) {
  int lane = threadIdx.x & 63;
  float a_s = ab_src[lane], b_s = ab_src[64 + lane];
  int r = __builtin_amdgcn_readfirstlane((blockIdx.x * blockDim.x + threadIdx.x) >> 6);
  if (r >= n) return;
  int beg = off[r], end = off[r + 1];
  float acc0 = 0.f, acc1 = 0.f;
  int e = beg;
  if (e < end && (e & 1)) {  // align to entry pair (16B)
    int2 p = ent[e];
    acc0 = fmaf(fmaf(srcf[p.x * DIM + lane], a_s, b_s), __int_as_float(p.y), acc0);
    ++e;
  }
  for (; e + 8 <= end; e += 8) {
    int4 p0 = *reinterpret_cast<const int4*>(&ent[e]);
    int4 p1 = *reinterpret_cast<const int4*>(&ent[e + 2]);
    int4 p2 = *reinterpret_cast<const int4*>(&ent[e + 4]);
    int4 p3 = *reinterpret_cast<const int4*>(&ent[e + 6]);
    float v0 = srcf[p0.x * DIM + lane];
    float v1 = srcf[p0.z * DIM + lane];
    float v2 = srcf[p1.x * DIM + lane];
    float v3 = srcf[p1.z * DIM + lane];
    float v4 = srcf[p2.x * DIM + lane];
    float v5 = srcf[p2.z * DIM + lane];
    float v6 = srcf[p3.x * DIM + lane];
    float v7 = srcf[p3.z * DIM + lane];
    acc0 = fmaf(fmaf(v0, a_s, b_s), __int_as_float(p0.y), acc0);
    acc1 = fmaf(fmaf(v1, a_s, b_s), __int_as_float(p0.w), acc1);
    acc0 = fmaf(fmaf(v2, a_s, b_s), __int_as_float(p1.y), acc0);
    acc1 = fmaf(fmaf(v3, a_s, b_s), __int_as_float(p1.w), acc1);
    acc0 = fmaf(fmaf(v4, a_s, b_s), __int_as_float(p2.y), acc0);
    acc1 = fmaf(fmaf(v5, a_s, b_s), __int_as_float(p2.w), acc1);
    acc0 = fmaf(fmaf(v6, a_s, b_s), __int_as_float(p3.y), acc0);
    acc1 = fmaf(fmaf(v7, a_s, b_s), __int_as_float(p3.w), acc1);
  }
  for (; e + 2 <= end; e += 2) {
    int4 p = *reinterpret_cast<const int4*>(&ent[e]);
    float v0 = srcf[p.x * DIM + lane];
    float v1 = srcf[p.z * DIM + lane];
    acc0 = fmaf(fmaf(v0, a_s, b_s), __int_as_float(p.y), acc0);
    acc1 = fmaf(fmaf(v1, a_s, b_s), __int_as_float(p.w), acc1);
  }
  if (e < end) {
    int2 p = ent[e];
    acc0 = fmaf(fmaf(srcf[p.x * DIM + lane], a_s, b_s), __int_as_float(p.y), acc0);
  }
  float acc = acc0 + acc1;
  agg[r * DIM + lane] = acc / fmaxf((float)(end - beg), 1.f);
}

// ---------------------------------------------------------------------------
// Output GEMM + epilogue in place; weights in registers, readlane broadcast.
// ---------------------------------------------------------------------------
__global__ __launch_bounds__(256) void out_k(
    const float* __restrict__ raw, const float* __restrict__ ab,
    const float* __restrict__ w_rel, const float* __restrict__ b_rel,
    const float* __restrict__ w_root, float* __restrict__ io, int n) {
  int lane = threadIdx.x & 63;
  float a = ab[lane], b = ab[64 + lane];
  float brel = b_rel[lane];
  float4 wr[16], wo[16];
#pragma unroll
  for (int i = 0; i < 16; ++i) {
    wr[i] = reinterpret_cast<const float4*>(w_rel + lane * DIM)[i];
    wo[i] = reinterpret_cast<const float4*>(w_root + lane * DIM)[i];
  }
  int wave = (blockIdx.x * blockDim.x + threadIdx.x) >> 6;
  int nw = (gridDim.x * blockDim.x) >> 6;
  for (int r = wave; r < n; r += nw) {
    float av = io[r * DIM + lane];
    float xv = fmaf(raw[r * DIM + lane], a, b);
    int avi = __float_as_int(av);
    int xvi = __float_as_int(xv);
    float acc0 = 0.f, acc1 = 0.f, acc2 = 0.f, acc3 = 0.f;
#pragma unroll
    for (int i = 0; i < 16; ++i) {
      acc0 = fmaf(__int_as_float(__builtin_amdgcn_readlane(avi, 4 * i + 0)), wr[i].x, acc0);
      acc1 = fmaf(__int_as_float(__builtin_amdgcn_readlane(avi, 4 * i + 1)), wr[i].y, acc1);
      acc2 = fmaf(__int_as_float(__builtin_amdgcn_readlane(avi, 4 * i + 2)), wr[i].z, acc2);
      acc3 = fmaf(__int_as_float(__builtin_amdgcn_readlane(avi, 4 * i + 3)), wr[i].w, acc3);
      acc0 = fmaf(__int_as_float(__builtin_amdgcn_readlane(xvi, 4 * i + 0)), wo[i].x, acc0);
      acc1 = fmaf(__int_as_float(__builtin_amdgcn_readlane(xvi, 4 * i + 1)), wo[i].y, acc1);
      acc2 = fmaf(__int_as_float(__builtin_amdgcn_readlane(xvi, 4 * i + 2)), wo[i].z, acc2);
      acc3 = fmaf(__int_as_float(__builtin_amdgcn_readlane(xvi, 4 * i + 3)), wo[i].w, acc3);
    }
    io[r * DIM + lane] = fmaxf((acc0 + acc1) + (acc2 + acc3) + brel + xv, 0.f);
  }
}

extern "C" void kernel_launch(void* const* d_in, const int* in_sizes, int n_in,
                              void* d_out, int out_size, void* d_ws, size_t ws_size,
                              hipStream_t stream) {
  const float* vf = (const float*)d_in[0];
  const float* cf = (const float*)d_in[1];
  const int* es = (const int*)d_in[2];
  const int* ed = (const int*)d_in[3];
  const float* ea = (const float*)d_in[4];
  const float* gn = (const float*)d_in[5];
  const float* bn = (const float*)d_in[6];
  const float* gc = (const float*)d_in[7];
  const float* bc = (const float*)d_in[8];
  const float* n_rel_w = (const float*)d_in[9];
  const float* n_rel_b = (const float*)d_in[10];
  const float* n_root_w = (const float*)d_in[11];
  const float* c_rel_w = (const float*)d_in[12];
  const float* c_rel_b = (const float*)d_in[13];
  const float* c_root_w = (const float*)d_in[14];
  float* out = (float*)d_out;
  int* wsi = (int*)d_ws;
  float* wsf = (float*)d_ws;

  float* stats = wsf + OFF_STATS;
  float* ab = wsf + OFF_AB;
  int* off_node = wsi + OFF_OFF_N;
  int* off_cstr = wsi + OFF_OFF_C;
  int* cur_node = wsi + OFF_CUR_N;
  int* cur_cstr = wsi + OFF_CUR_C;
  int* deg_node = wsi + OFF_DEG_N;
  int* deg_cstr = wsi + OFF_DEG_C;
  int2* ent_node = (int2*)(wsi + OFF_ENT_N);
  int2* ent_cstr = (int2*)(wsi + OFF_ENT_C);

  float* agg_node = out;            // d_out rows reused as agg scratch
  float* agg_cstr = out + 6400000;

  hipMemsetAsync(d_ws, 0, (size_t)WS_ZERO_N * sizeof(int), stream);

  bn_stats_k<<<512, 256, 0, stream>>>(vf, N_VAR, stats);
  bn_stats_k<<<512, 256, 0, stream>>>(cf, N_CSTR, stats + 128);
  bn_finalize_k<<<1, 128, 0, stream>>>(stats, gn, bn, gc, bc, ab);

  hist_k<<<(NEDGE / 4 + 255) / 256, 256, 0, stream>>>((const int4*)es, (const int4*)ed,
                                                      deg_node, deg_cstr);
  scan_part_k<<<NB_T, 256, 0, stream>>>(wsi);
  scan_meta_k<<<1, 256, 0, stream>>>(wsi);
  scan_apply_k<<<NB_T, 256, 0, stream>>>(wsi);
  fill_k<<<(NEDGE / 4 + 255) / 256, 256, 0, stream>>>((const int4*)es, (const int4*)ed,
                                                      (const float4*)ea, cur_node,
                                                      cur_cstr, ent_node, ent_cstr);

  gather_k<<<(N_VAR + 3) / 4, 256, 0, stream>>>(cf, ent_node, off_node, ab + 128,
                                                agg_node, N_VAR);
  gather_k<<<(N_CSTR + 3) / 4, 256, 0, stream>>>(vf, ent_cstr, off_cstr, ab,
                                                 agg_cstr, N_CSTR);

  out_k<<<1024, 256, 0, stream>>>(vf, ab, n_rel_w, n_rel_b, n_root_w, agg_node, N_VAR);
  out_k<<<512, 256, 0, stream>>>(cf, ab + 128, c_rel_w, c_rel_b, c_root_w, agg_cstr,
                                 N_CSTR);
}